// Round 1
// baseline (571.430 us; speedup 1.0000x reference)
//
#include <hip/hip_runtime.h>

// GCN layer: H = X @ W^T ; out = A_coo @ H
// N=50000 nodes, E=1600000 edges, F=128 features (in == out).
//
// Strategy: build CSR each launch (histogram -> scan -> scatter), then
// pull-style SpMM (one wave per destination row, no feature-space atomics).
// Fallback: atomicAdd scatter if ws too small for CSR scratch.

constexpr int N_NODES = 50000;
constexpr int N_EDGES = 1600000;
constexpr int FEAT    = 128;

// ---------------------------------------------------------------------------
// GEMM: H[n,o] = sum_k X[n,k] * W[o,k]   (X:[N,128], W:[128,128] row-major)
// Block tile 64 rows x 128 cols, 256 threads, thread tile 4x8.
// Col mapping per thread: cols {tx + 16*j} keeps LDS reads conflict-free
// (stride-33 rows => bank = (row + k) % 32, distinct per lane).
// ---------------------------------------------------------------------------
__global__ __launch_bounds__(256) void gemm_xwt(const float* __restrict__ X,
                                                const float* __restrict__ W,
                                                float* __restrict__ H) {
    constexpr int BM = 64, BK = 32;
    __shared__ float Xs[BM][BK + 1];
    __shared__ float Ws[FEAT][BK + 1];

    const int tid = threadIdx.x;
    const int tx  = tid & 15;   // col group 0..15
    const int ty  = tid >> 4;   // row group 0..15
    const int row0 = blockIdx.x * BM;

    float acc[4][8];
#pragma unroll
    for (int i = 0; i < 4; i++)
#pragma unroll
        for (int j = 0; j < 8; j++) acc[i][j] = 0.f;

    for (int kt = 0; kt < FEAT; kt += BK) {
        // Stage X tile: 64x32 floats = 512 float4, 2 per thread.
#pragma unroll
        for (int t = 0; t < 2; t++) {
            int idx = tid + 256 * t;       // float4 index
            int r   = idx >> 3;            // 8 float4 per row
            int kq  = (idx & 7) << 2;
            int gr  = row0 + r;
            if (gr >= N_NODES) gr = N_NODES - 1;  // clamp (unused rows not stored)
            const float4 v = *(const float4*)&X[gr * FEAT + kt + kq];
            Xs[r][kq + 0] = v.x; Xs[r][kq + 1] = v.y;
            Xs[r][kq + 2] = v.z; Xs[r][kq + 3] = v.w;
        }
        // Stage W tile: 128x32 floats = 1024 float4, 4 per thread.
#pragma unroll
        for (int t = 0; t < 4; t++) {
            int idx = tid + 256 * t;
            int r   = idx >> 3;
            int kq  = (idx & 7) << 2;
            const float4 v = *(const float4*)&W[r * FEAT + kt + kq];
            Ws[r][kq + 0] = v.x; Ws[r][kq + 1] = v.y;
            Ws[r][kq + 2] = v.z; Ws[r][kq + 3] = v.w;
        }
        __syncthreads();

#pragma unroll
        for (int k = 0; k < BK; k++) {
            float xv[4], wv[8];
#pragma unroll
            for (int i = 0; i < 4; i++) xv[i] = Xs[ty * 4 + i][k];
#pragma unroll
            for (int j = 0; j < 8; j++) wv[j] = Ws[tx + 16 * j][k];
#pragma unroll
            for (int i = 0; i < 4; i++)
#pragma unroll
                for (int j = 0; j < 8; j++) acc[i][j] += xv[i] * wv[j];
        }
        __syncthreads();
    }

#pragma unroll
    for (int i = 0; i < 4; i++) {
        int gr = row0 + ty * 4 + i;
        if (gr < N_NODES) {
#pragma unroll
            for (int j = 0; j < 8; j++) H[gr * FEAT + tx + 16 * j] = acc[i][j];
        }
    }
}

// ---------------------------------------------------------------------------
// CSR build: histogram -> single-block scan -> scatter
// ---------------------------------------------------------------------------
__global__ void hist_rows(const int* __restrict__ rows, int* __restrict__ counts) {
    int e = blockIdx.x * blockDim.x + threadIdx.x;
    if (e < N_EDGES) atomicAdd(&counts[rows[e]], 1);
}

__global__ __launch_bounds__(1024) void scan_counts(const int* __restrict__ counts,
                                                    int* __restrict__ row_start) {
    __shared__ int sums[1024];
    const int t  = threadIdx.x;
    const int CH = (N_NODES + 1023) / 1024;  // 49
    const int base = t * CH;

    int s = 0;
    for (int i = 0; i < CH; i++) {
        int idx = base + i;
        if (idx < N_NODES) s += counts[idx];
    }
    sums[t] = s;
    __syncthreads();
    // Hillis-Steele inclusive scan over 1024 partials
    for (int off = 1; off < 1024; off <<= 1) {
        int v = (t >= off) ? sums[t - off] : 0;
        __syncthreads();
        sums[t] += v;
        __syncthreads();
    }
    int run = (t == 0) ? 0 : sums[t - 1];  // exclusive prefix of this chunk
    for (int i = 0; i < CH; i++) {
        int idx = base + i;
        if (idx < N_NODES) {
            row_start[idx] = run;
            run += counts[idx];
        }
    }
    if (t == 0) row_start[N_NODES] = sums[1023];  // == N_EDGES
}

__global__ void scatter_edges(const int* __restrict__ rows, const int* __restrict__ cols,
                              const float* __restrict__ vals,
                              const int* __restrict__ row_start, int* __restrict__ cursor,
                              int* __restrict__ scol, float* __restrict__ sval) {
    int e = blockIdx.x * blockDim.x + threadIdx.x;
    if (e >= N_EDGES) return;
    int r   = rows[e];
    int pos = row_start[r] + atomicAdd(&cursor[r], 1);
    scol[pos] = cols[e];
    sval[pos] = vals[e];
}

// ---------------------------------------------------------------------------
// Pull SpMM: one wave per destination row, float2 per lane (128 floats/row).
// ---------------------------------------------------------------------------
__global__ __launch_bounds__(256) void spmm_csr(const int* __restrict__ row_start,
                                                const int* __restrict__ scol,
                                                const float* __restrict__ sval,
                                                const float* __restrict__ H,
                                                float* __restrict__ out) {
    const int wave = blockIdx.x * 4 + (threadIdx.x >> 6);
    const int lane = threadIdx.x & 63;
    if (wave >= N_NODES) return;

    const int beg = row_start[wave];
    const int end = row_start[wave + 1];
    const float2* __restrict__ H2 = (const float2*)H;

    float2 acc = {0.f, 0.f};
    for (int e = beg; e < end; e++) {
        const int   c = scol[e];
        const float v = sval[e];
        const float2 h = H2[c * 64 + lane];
        acc.x += v * h.x;
        acc.y += v * h.y;
    }
    ((float2*)out)[wave * 64 + lane] = acc;
}

// Fallback: feature-space atomics (only if ws too small for CSR scratch).
__global__ __launch_bounds__(256) void spmm_atomic(const int* __restrict__ rows,
                                                   const int* __restrict__ cols,
                                                   const float* __restrict__ vals,
                                                   const float* __restrict__ H,
                                                   float* __restrict__ out) {
    const int e    = blockIdx.x * 4 + (threadIdx.x >> 6);
    const int lane = threadIdx.x & 63;
    if (e >= N_EDGES) return;
    const int   r = rows[e];
    const int   c = cols[e];
    const float v = vals[e];
    const float2* H2 = (const float2*)H;
    const float2 h = H2[c * 64 + lane];
    atomicAdd(&out[r * FEAT + lane * 2 + 0], v * h.x);
    atomicAdd(&out[r * FEAT + lane * 2 + 1], v * h.y);
}

// ---------------------------------------------------------------------------
extern "C" void kernel_launch(void* const* d_in, const int* in_sizes, int n_in,
                              void* d_out, int out_size, void* d_ws, size_t ws_size,
                              hipStream_t stream) {
    const float* X      = (const float*)d_in[0];
    const float* W      = (const float*)d_in[1];
    const float* A_vals = (const float*)d_in[2];
    const int*   A_rows = (const int*)d_in[3];
    const int*   A_cols = (const int*)d_in[4];
    float* out = (float*)d_out;

    // ws layout (256B aligned slices)
    auto align256 = [](size_t x) { return (x + 255) & ~size_t(255); };
    size_t off = 0;
    size_t h_off = off;      off += align256(size_t(N_NODES) * FEAT * sizeof(float));
    size_t cnt_off = off;    off += align256(size_t(N_NODES) * sizeof(int));
    size_t cur_off = off;    off += align256(size_t(N_NODES) * sizeof(int));
    size_t rs_off = off;     off += align256(size_t(N_NODES + 1) * sizeof(int));
    size_t scol_off = off;   off += align256(size_t(N_EDGES) * sizeof(int));
    size_t sval_off = off;   off += align256(size_t(N_EDGES) * sizeof(float));
    const size_t need_full = off;
    const size_t need_h    = align256(size_t(N_NODES) * FEAT * sizeof(float));

    char* ws = (char*)d_ws;
    float* H = (float*)(ws + h_off);

    // GEMM: H = X @ W^T
    gemm_xwt<<<(N_NODES + 63) / 64, 256, 0, stream>>>(X, W, H);

    if (ws_size >= need_full) {
        int*   counts    = (int*)(ws + cnt_off);
        int*   cursor    = (int*)(ws + cur_off);
        int*   row_start = (int*)(ws + rs_off);
        int*   scol      = (int*)(ws + scol_off);
        float* sval      = (float*)(ws + sval_off);

        // counts and cursor are adjacent -> one memset covers both regions
        hipMemsetAsync(ws + cnt_off, 0, cur_off - cnt_off + align256(size_t(N_NODES) * sizeof(int)), stream);

        hist_rows<<<(N_EDGES + 255) / 256, 256, 0, stream>>>(A_rows, counts);
        scan_counts<<<1, 1024, 0, stream>>>(counts, row_start);
        scatter_edges<<<(N_EDGES + 255) / 256, 256, 0, stream>>>(A_rows, A_cols, A_vals,
                                                                 row_start, cursor, scol, sval);
        spmm_csr<<<(N_NODES + 3) / 4, 256, 0, stream>>>(row_start, scol, sval, H, out);
    } else if (ws_size >= need_h) {
        hipMemsetAsync(out, 0, size_t(N_NODES) * FEAT * sizeof(float), stream);
        spmm_atomic<<<(N_EDGES + 3) / 4, 256, 0, stream>>>(A_rows, A_cols, A_vals, H, out);
    }
    // (if ws can't even hold H, there is no viable path — harness provides scratch)
}

// Round 2
// 399.229 us; speedup vs baseline: 1.4313x; 1.4313x over previous
//
#include <hip/hip_runtime.h>

// GCN layer: H = X @ W^T ; out = A_coo @ H
// N=50000, E=1600000, F=128.
//
// Padded-bucket counting scatter (no hist/scan) + feature-chunked pull SpMM
// (8 chunks of 16 feats; 3.2MB H-slice fits per-XCD L2, chunk-major dispatch).

constexpr int N_NODES = 50000;
constexpr int N_EDGES = 1600000;
constexpr int FEAT    = 128;

constexpr int GEMM_BLOCKS = (N_NODES + 63) / 64;    // 782
constexpr int SCAT_BLOCKS = (N_EDGES + 255) / 256;  // 6250
constexpr int ROWB        = (N_NODES + 15) / 16;    // 3125 row-blocks (16 rows/block)
constexpr int OVF_CAP     = 8192;

// ---------------------------------------------------------------------------
// GEMM body: H[n,o] = sum_k X[n,k] * W[o,k]. 64x128 tile, 256 thr, 4x8/thread.
// ---------------------------------------------------------------------------
__device__ void gemm_body(const float* __restrict__ X, const float* __restrict__ W,
                          float* __restrict__ H, int block) {
    constexpr int BM = 64, BK = 32;
    __shared__ float Xs[BM][BK + 1];
    __shared__ float Ws[FEAT][BK + 1];

    const int tid = threadIdx.x;
    const int tx  = tid & 15;
    const int ty  = tid >> 4;
    const int row0 = block * BM;

    float acc[4][8];
#pragma unroll
    for (int i = 0; i < 4; i++)
#pragma unroll
        for (int j = 0; j < 8; j++) acc[i][j] = 0.f;

    for (int kt = 0; kt < FEAT; kt += BK) {
#pragma unroll
        for (int t = 0; t < 2; t++) {
            int idx = tid + 256 * t;
            int r   = idx >> 3;
            int kq  = (idx & 7) << 2;
            int gr  = row0 + r;
            if (gr >= N_NODES) gr = N_NODES - 1;
            const float4 v = *(const float4*)&X[gr * FEAT + kt + kq];
            Xs[r][kq + 0] = v.x; Xs[r][kq + 1] = v.y;
            Xs[r][kq + 2] = v.z; Xs[r][kq + 3] = v.w;
        }
#pragma unroll
        for (int t = 0; t < 4; t++) {
            int idx = tid + 256 * t;
            int r   = idx >> 3;
            int kq  = (idx & 7) << 2;
            const float4 v = *(const float4*)&W[r * FEAT + kt + kq];
            Ws[r][kq + 0] = v.x; Ws[r][kq + 1] = v.y;
            Ws[r][kq + 2] = v.z; Ws[r][kq + 3] = v.w;
        }
        __syncthreads();

#pragma unroll
        for (int k = 0; k < BK; k++) {
            float xv[4], wv[8];
#pragma unroll
            for (int i = 0; i < 4; i++) xv[i] = Xs[ty * 4 + i][k];
#pragma unroll
            for (int j = 0; j < 8; j++) wv[j] = Ws[tx + 16 * j][k];
#pragma unroll
            for (int i = 0; i < 4; i++)
#pragma unroll
                for (int j = 0; j < 8; j++) acc[i][j] += xv[i] * wv[j];
        }
        __syncthreads();
    }

#pragma unroll
    for (int i = 0; i < 4; i++) {
        int gr = row0 + ty * 4 + i;
        if (gr < N_NODES) {
#pragma unroll
            for (int j = 0; j < 8; j++) H[gr * FEAT + tx + 16 * j] = acc[i][j];
        }
    }
}

// ---------------------------------------------------------------------------
// Padded path: fused GEMM + bucket-scatter (blocks [0,GEMM_BLOCKS) do GEMM,
// the rest scatter one edge/thread into row buckets of `slots` entries).
// ---------------------------------------------------------------------------
__global__ __launch_bounds__(256) void gemm_scatter_padded(
    const float* __restrict__ X, const float* __restrict__ W, float* __restrict__ H,
    const int* __restrict__ rows, const int* __restrict__ cols, const float* __restrict__ vals,
    int* __restrict__ cursor, int2* __restrict__ sbuf, int slots,
    int* __restrict__ ovf_cnt, int* __restrict__ ovf) {
    if (blockIdx.x < GEMM_BLOCKS) {
        gemm_body(X, W, H, blockIdx.x);
        return;
    }
    int e = (blockIdx.x - GEMM_BLOCKS) * 256 + threadIdx.x;
    if (e >= N_EDGES) return;
    int r    = rows[e];
    int rank = atomicAdd(&cursor[r], 1);
    if (rank < slots) {
        sbuf[r * slots + rank] = make_int2(cols[e], __float_as_int(vals[e]));
    } else {
        int k = atomicAdd(ovf_cnt, 1);
        if (k < OVF_CAP) ovf[k] = e;
    }
}

// ---------------------------------------------------------------------------
// Exact path (fallback, small ws): fused GEMM + histogram, then scan, scatter.
// ---------------------------------------------------------------------------
__global__ __launch_bounds__(256) void gemm_hist(
    const float* __restrict__ X, const float* __restrict__ W, float* __restrict__ H,
    const int* __restrict__ rows, int* __restrict__ counts) {
    if (blockIdx.x < GEMM_BLOCKS) {
        gemm_body(X, W, H, blockIdx.x);
        return;
    }
    int e = (blockIdx.x - GEMM_BLOCKS) * 256 + threadIdx.x;
    if (e < N_EDGES) atomicAdd(&counts[rows[e]], 1);
}

__global__ __launch_bounds__(1024) void scan_counts(const int* __restrict__ counts,
                                                    int* __restrict__ row_start) {
    __shared__ int sums[1024];
    const int t  = threadIdx.x;
    const int CH = (N_NODES + 1023) / 1024;
    const int base = t * CH;

    int s = 0;
    for (int i = 0; i < CH; i++) {
        int idx = base + i;
        if (idx < N_NODES) s += counts[idx];
    }
    sums[t] = s;
    __syncthreads();
    for (int off = 1; off < 1024; off <<= 1) {
        int v = (t >= off) ? sums[t - off] : 0;
        __syncthreads();
        sums[t] += v;
        __syncthreads();
    }
    int run = (t == 0) ? 0 : sums[t - 1];
    for (int i = 0; i < CH; i++) {
        int idx = base + i;
        if (idx < N_NODES) {
            row_start[idx] = run;
            run += counts[idx];
        }
    }
    if (t == 0) row_start[N_NODES] = sums[1023];
}

__global__ void scatter_exact(const int* __restrict__ rows, const int* __restrict__ cols,
                              const float* __restrict__ vals,
                              const int* __restrict__ row_start, int* __restrict__ cursor,
                              int2* __restrict__ sbuf) {
    int e = blockIdx.x * blockDim.x + threadIdx.x;
    if (e >= N_EDGES) return;
    int r   = rows[e];
    int pos = row_start[r] + atomicAdd(&cursor[r], 1);
    sbuf[pos] = make_int2(cols[e], __float_as_int(vals[e]));
}

// ---------------------------------------------------------------------------
// Feature-chunked pull SpMM. 8 chunks x 16 feats; chunk-major dispatch so one
// 3.2MB H-slice is L2-resident per phase. Quarter-wave (16 lanes) per row:
// one 64B line per edge gather. slots>0 -> padded buckets; slots==0 -> CSR.
// ---------------------------------------------------------------------------
__global__ __launch_bounds__(256) void spmm_chunked(
    const int* __restrict__ row_start, const int* __restrict__ cursor,
    const int2* __restrict__ sbuf, const float* __restrict__ H,
    float* __restrict__ out, int slots) {
    const int tid   = threadIdx.x;
    const int lane  = tid & 63;
    const int wave  = tid >> 6;
    const int chunk = blockIdx.x / ROWB;             // 0..7, chunk-major
    const int rb    = blockIdx.x - chunk * ROWB;
    const int row   = rb * 16 + wave * 4 + (lane >> 4);
    const int f     = lane & 15;
    if (row >= N_NODES) return;

    int base, deg;
    if (slots > 0) {
        base = row * slots;
        int c = cursor[row];
        deg = c < slots ? c : slots;
    } else {
        base = row_start[row];
        deg  = row_start[row + 1] - base;
    }
    const int fo = chunk * 16 + f;

    float acc = 0.f;
    int i = 0;
    for (; i + 2 <= deg; i += 2) {
        int2 m0 = sbuf[base + i];
        int2 m1 = sbuf[base + i + 1];
        float h0 = H[m0.x * FEAT + fo];
        float h1 = H[m1.x * FEAT + fo];
        acc += __int_as_float(m0.y) * h0;
        acc += __int_as_float(m1.y) * h1;
    }
    if (i < deg) {
        int2 m = sbuf[base + i];
        acc += __int_as_float(m.y) * H[m.x * FEAT + fo];
    }
    out[row * FEAT + fo] = acc;
}

// Overflow fixup (padded path): typically 0 entries; exact correctness net.
__global__ void fixup_ovf(const int* __restrict__ ovf_cnt, const int* __restrict__ ovf,
                          const int* __restrict__ rows, const int* __restrict__ cols,
                          const float* __restrict__ vals,
                          const float* __restrict__ H, float* __restrict__ out) {
    int n = *ovf_cnt;
    if (n > OVF_CAP) n = OVF_CAP;
    for (int k = blockIdx.x; k < n; k += gridDim.x) {
        int e = ovf[k];
        int r = rows[e], c = cols[e];
        float v = vals[e];
        for (int f = threadIdx.x; f < FEAT; f += blockDim.x)
            atomicAdd(&out[r * FEAT + f], v * H[c * FEAT + f]);
    }
}

// ---------------------------------------------------------------------------
extern "C" void kernel_launch(void* const* d_in, const int* in_sizes, int n_in,
                              void* d_out, int out_size, void* d_ws, size_t ws_size,
                              hipStream_t stream) {
    const float* X      = (const float*)d_in[0];
    const float* W      = (const float*)d_in[1];
    const float* A_vals = (const float*)d_in[2];
    const int*   A_rows = (const int*)d_in[3];
    const int*   A_cols = (const int*)d_in[4];
    float* out = (float*)d_out;

    auto align256 = [](size_t x) { return (x + 255) & ~size_t(255); };
    char* ws = (char*)d_ws;

    const size_t h_bytes = align256(size_t(N_NODES) * FEAT * sizeof(float));   // 25.6MB
    float* H = (float*)ws;

    // ---- padded-path layout ----
    size_t off = h_bytes;
    size_t cur_off  = off; off += align256(size_t(N_NODES) * sizeof(int));
    size_t ovfc_off = off; off += 256;
    size_t ovf_off  = off; off += align256(size_t(OVF_CAP) * sizeof(int));
    size_t sbuf_off = off;
    const size_t fixed = off;
    int slots = 0;
    if (ws_size > fixed) {
        size_t s = (ws_size - fixed) / (size_t(N_NODES) * sizeof(int2));
        slots = (int)(s > 96 ? 96 : s);
        slots &= ~1;  // even -> 16B-aligned bucket bases
    }

    if (slots >= 64) {
        int*  cursor  = (int*)(ws + cur_off);
        int*  ovf_cnt = (int*)(ws + ovfc_off);
        int*  ovf     = (int*)(ws + ovf_off);
        int2* sbuf    = (int2*)(ws + sbuf_off);

        // zero cursor + ovf_cnt in one contiguous memset
        hipMemsetAsync(ws + cur_off, 0, (ovfc_off - cur_off) + 256, stream);
        gemm_scatter_padded<<<GEMM_BLOCKS + SCAT_BLOCKS, 256, 0, stream>>>(
            X, W, H, A_rows, A_cols, A_vals, cursor, sbuf, slots, ovf_cnt, ovf);
        spmm_chunked<<<ROWB * 8, 256, 0, stream>>>(nullptr, cursor, sbuf, H, out, slots);
        fixup_ovf<<<16, 256, 0, stream>>>(ovf_cnt, ovf, A_rows, A_cols, A_vals, H, out);
    } else {
        // ---- exact-CSR fallback layout ----
        size_t o2 = h_bytes;
        size_t cnt_off = o2; o2 += align256(size_t(N_NODES) * sizeof(int));
        size_t cu2_off = o2; o2 += align256(size_t(N_NODES) * sizeof(int));
        size_t rs_off  = o2; o2 += align256(size_t(N_NODES + 1) * sizeof(int));
        size_t sb2_off = o2; o2 += size_t(N_EDGES) * sizeof(int2);

        int*  counts    = (int*)(ws + cnt_off);
        int*  cursor    = (int*)(ws + cu2_off);
        int*  row_start = (int*)(ws + rs_off);
        int2* sbuf      = (int2*)(ws + sb2_off);

        hipMemsetAsync(ws + cnt_off, 0, cu2_off - cnt_off + align256(size_t(N_NODES) * sizeof(int)), stream);
        gemm_hist<<<GEMM_BLOCKS + SCAT_BLOCKS, 256, 0, stream>>>(X, W, H, A_rows, counts);
        scan_counts<<<1, 1024, 0, stream>>>(counts, row_start);
        scatter_exact<<<SCAT_BLOCKS, 256, 0, stream>>>(A_rows, A_cols, A_vals,
                                                       row_start, cursor, sbuf);
        spmm_chunked<<<ROWB * 8, 256, 0, stream>>>(row_start, nullptr, sbuf, H, out, 0);
    }
}

// Round 3
// 360.051 us; speedup vs baseline: 1.5871x; 1.1088x over previous
//
#include <hip/hip_runtime.h>

// GCN layer: H = X @ W^T ; out = A_coo @ H
// N=50000, E=1600000, F=128.
//
// Padded-bucket counting scatter + whole-row pull SpMM with LDS-staged edge
// entries and 8-deep unrolled gathers (MLP against L2-miss latency).

constexpr int N_NODES = 50000;
constexpr int N_EDGES = 1600000;
constexpr int FEAT    = 128;

constexpr int GEMM_BLOCKS = (N_NODES + 63) / 64;        // 782
constexpr int SCAT_BLOCKS = (N_EDGES / 4 + 255) / 256;  // 1563 (4 edges/thread)
constexpr int OVF_CAP     = 8192;

// ---------------------------------------------------------------------------
// GEMM body: H[n,o] = sum_k X[n,k] * W[o,k]. 64x128 tile, 256 thr, 4x8/thread.
// ---------------------------------------------------------------------------
__device__ void gemm_body(const float* __restrict__ X, const float* __restrict__ W,
                          float* __restrict__ H, int block) {
    constexpr int BM = 64, BK = 32;
    __shared__ float Xs[BM][BK + 1];
    __shared__ float Ws[FEAT][BK + 1];

    const int tid = threadIdx.x;
    const int tx  = tid & 15;
    const int ty  = tid >> 4;
    const int row0 = block * BM;

    float acc[4][8];
#pragma unroll
    for (int i = 0; i < 4; i++)
#pragma unroll
        for (int j = 0; j < 8; j++) acc[i][j] = 0.f;

    for (int kt = 0; kt < FEAT; kt += BK) {
#pragma unroll
        for (int t = 0; t < 2; t++) {
            int idx = tid + 256 * t;
            int r   = idx >> 3;
            int kq  = (idx & 7) << 2;
            int gr  = row0 + r;
            if (gr >= N_NODES) gr = N_NODES - 1;
            const float4 v = *(const float4*)&X[gr * FEAT + kt + kq];
            Xs[r][kq + 0] = v.x; Xs[r][kq + 1] = v.y;
            Xs[r][kq + 2] = v.z; Xs[r][kq + 3] = v.w;
        }
#pragma unroll
        for (int t = 0; t < 4; t++) {
            int idx = tid + 256 * t;
            int r   = idx >> 3;
            int kq  = (idx & 7) << 2;
            const float4 v = *(const float4*)&W[r * FEAT + kt + kq];
            Ws[r][kq + 0] = v.x; Ws[r][kq + 1] = v.y;
            Ws[r][kq + 2] = v.z; Ws[r][kq + 3] = v.w;
        }
        __syncthreads();

#pragma unroll
        for (int k = 0; k < BK; k++) {
            float xv[4], wv[8];
#pragma unroll
            for (int i = 0; i < 4; i++) xv[i] = Xs[ty * 4 + i][k];
#pragma unroll
            for (int j = 0; j < 8; j++) wv[j] = Ws[tx + 16 * j][k];
#pragma unroll
            for (int i = 0; i < 4; i++)
#pragma unroll
                for (int j = 0; j < 8; j++) acc[i][j] += xv[i] * wv[j];
        }
        __syncthreads();
    }

#pragma unroll
    for (int i = 0; i < 4; i++) {
        int gr = row0 + ty * 4 + i;
        if (gr < N_NODES) {
#pragma unroll
            for (int j = 0; j < 8; j++) H[gr * FEAT + tx + 16 * j] = acc[i][j];
        }
    }
}

// GEMM + zero the cursor/count arrays for the kernel that follows (saves a
// memset dispatch; stream order guarantees visibility).
__global__ __launch_bounds__(256) void gemm_xwt_zero(const float* __restrict__ X,
                                                     const float* __restrict__ W,
                                                     float* __restrict__ H,
                                                     int* __restrict__ zbuf, int zn) {
    int t = blockIdx.x * 256 + threadIdx.x;
    if (t < zn) zbuf[t] = 0;
    gemm_body(X, W, H, blockIdx.x);
}

// ---------------------------------------------------------------------------
// Padded bucket scatter: 4 edges/thread, int4 vector reads, NT packed stores.
// ---------------------------------------------------------------------------
__global__ __launch_bounds__(256) void scatter_padded(
    const int* __restrict__ rows, const int* __restrict__ cols,
    const float* __restrict__ vals,
    int* __restrict__ cursor, long long* __restrict__ sbuf, int slots,
    int* __restrict__ ovf_cnt, int* __restrict__ ovf) {
    int e0 = (blockIdx.x * 256 + threadIdx.x) * 4;
    if (e0 >= N_EDGES) return;
    const int4   r4 = *(const int4*)&rows[e0];
    const int4   c4 = *(const int4*)&cols[e0];
    const float4 v4 = *(const float4*)&vals[e0];
    const int   r[4] = {r4.x, r4.y, r4.z, r4.w};
    const int   c[4] = {c4.x, c4.y, c4.z, c4.w};
    const float v[4] = {v4.x, v4.y, v4.z, v4.w};
#pragma unroll
    for (int j = 0; j < 4; j++) {
        int rank = atomicAdd(&cursor[r[j]], 1);
        if (rank < slots) {
            long long m = ((long long)__float_as_int(v[j]) << 32) | (unsigned int)c[j];
            __builtin_nontemporal_store(m, &sbuf[(size_t)r[j] * slots + rank]);
        } else {
            int k = atomicAdd(ovf_cnt, 1);
            if (k < OVF_CAP) ovf[k] = e0 + j;
        }
    }
}

// ---------------------------------------------------------------------------
// Exact path (fallback, small ws): GEMM+zero, histogram, scan, scatter.
// ---------------------------------------------------------------------------
__global__ void hist_rows(const int* __restrict__ rows, int* __restrict__ counts) {
    int e = blockIdx.x * blockDim.x + threadIdx.x;
    if (e < N_EDGES) atomicAdd(&counts[rows[e]], 1);
}

__global__ __launch_bounds__(1024) void scan_counts(const int* __restrict__ counts,
                                                    int* __restrict__ row_start) {
    __shared__ int sums[1024];
    const int t  = threadIdx.x;
    const int CH = (N_NODES + 1023) / 1024;
    const int base = t * CH;
    int s = 0;
    for (int i = 0; i < CH; i++) {
        int idx = base + i;
        if (idx < N_NODES) s += counts[idx];
    }
    sums[t] = s;
    __syncthreads();
    for (int off = 1; off < 1024; off <<= 1) {
        int v = (t >= off) ? sums[t - off] : 0;
        __syncthreads();
        sums[t] += v;
        __syncthreads();
    }
    int run = (t == 0) ? 0 : sums[t - 1];
    for (int i = 0; i < CH; i++) {
        int idx = base + i;
        if (idx < N_NODES) {
            row_start[idx] = run;
            run += counts[idx];
        }
    }
    if (t == 0) row_start[N_NODES] = sums[1023];
}

__global__ void scatter_exact(const int* __restrict__ rows, const int* __restrict__ cols,
                              const float* __restrict__ vals,
                              const int* __restrict__ row_start, int* __restrict__ cursor,
                              long long* __restrict__ sbuf) {
    int e = blockIdx.x * blockDim.x + threadIdx.x;
    if (e >= N_EDGES) return;
    int r   = rows[e];
    int pos = row_start[r] + atomicAdd(&cursor[r], 1);
    long long m = ((long long)__float_as_int(vals[e]) << 32) | (unsigned int)cols[e];
    sbuf[pos] = m;
}

// ---------------------------------------------------------------------------
// Pull SpMM: 1 wave = 1 row, float2 per lane (whole 512B row per gather).
// Edge (col,val) entries staged 64-at-a-time into LDS by one coalesced load;
// edge loop unrolled x8 so 8 independent H-row gathers are in flight.
// ---------------------------------------------------------------------------
__global__ __launch_bounds__(256) void spmm_pull(
    const int* __restrict__ row_start, const int* __restrict__ cursor,
    const int2* __restrict__ sbuf, const float* __restrict__ H,
    float* __restrict__ out, int slots) {
    __shared__ int2 elds[4][64];
    const int wv   = threadIdx.x >> 6;
    const int lane = threadIdx.x & 63;
    const int row  = blockIdx.x * 4 + wv;
    if (row >= N_NODES) return;

    int base, deg;
    if (slots > 0) {
        base = row * slots;
        int cc = cursor[row];
        deg = cc < slots ? cc : slots;
    } else {
        base = row_start[row];
        deg  = row_start[row + 1] - base;
    }
    const float2* __restrict__ H2 = (const float2*)H;

    float2 acc = {0.f, 0.f};
    for (int b = 0; b < deg; b += 64) {
        const int n = (deg - b) < 64 ? (deg - b) : 64;
        if (lane < n) elds[wv][lane] = sbuf[base + b + lane];
        int i = 0;
        for (; i + 8 <= n; i += 8) {
            float2 h[8];
            float  v[8];
#pragma unroll
            for (int j = 0; j < 8; j++) {
                const int2 m = elds[wv][i + j];
                v[j] = __int_as_float(m.y);
                h[j] = H2[m.x * 64 + lane];
            }
#pragma unroll
            for (int j = 0; j < 8; j++) {
                acc.x += v[j] * h[j].x;
                acc.y += v[j] * h[j].y;
            }
        }
        for (; i < n; i++) {
            const int2 m = elds[wv][i];
            const float2 h = H2[m.x * 64 + lane];
            acc.x += __int_as_float(m.y) * h.x;
            acc.y += __int_as_float(m.y) * h.y;
        }
    }
    ((float2*)out)[row * 64 + lane] = acc;
}

// Overflow fixup (padded path): expected 0 entries; exact correctness net.
__global__ void fixup_ovf(const int* __restrict__ ovf_cnt, const int* __restrict__ ovf,
                          const int* __restrict__ rows, const int* __restrict__ cols,
                          const float* __restrict__ vals,
                          const float* __restrict__ H, float* __restrict__ out) {
    int n = *ovf_cnt;
    if (n > OVF_CAP) n = OVF_CAP;
    for (int k = blockIdx.x; k < n; k += gridDim.x) {
        int e = ovf[k];
        int r = rows[e], c = cols[e];
        float v = vals[e];
        for (int f = threadIdx.x; f < FEAT; f += blockDim.x)
            atomicAdd(&out[r * FEAT + f], v * H[c * FEAT + f]);
    }
}

// ---------------------------------------------------------------------------
extern "C" void kernel_launch(void* const* d_in, const int* in_sizes, int n_in,
                              void* d_out, int out_size, void* d_ws, size_t ws_size,
                              hipStream_t stream) {
    const float* X      = (const float*)d_in[0];
    const float* W      = (const float*)d_in[1];
    const float* A_vals = (const float*)d_in[2];
    const int*   A_rows = (const int*)d_in[3];
    const int*   A_cols = (const int*)d_in[4];
    float* out = (float*)d_out;

    auto align256 = [](size_t x) { return (x + 255) & ~size_t(255); };
    char* ws = (char*)d_ws;

    const size_t h_bytes = align256(size_t(N_NODES) * FEAT * sizeof(float));   // 25.6MB
    float* H = (float*)ws;

    // ---- padded-path layout: [H][cursor][ovf_cnt][ovf][sbuf] ----
    size_t off = h_bytes;
    size_t cur_off  = off; off += align256(size_t(N_NODES) * sizeof(int));
    size_t ovfc_off = off; off += 256;
    size_t ovf_off  = off; off += align256(size_t(OVF_CAP) * sizeof(int));
    size_t sbuf_off = off;
    const size_t fixed = off;
    int slots = 0;
    if (ws_size > fixed) {
        size_t s = (ws_size - fixed) / (size_t(N_NODES) * sizeof(long long));
        slots = (int)(s > 96 ? 96 : s);
        slots &= ~1;
    }

    if (slots >= 64) {
        int*       cursor  = (int*)(ws + cur_off);
        int*       ovf_cnt = (int*)(ws + ovfc_off);
        int*       ovf     = (int*)(ws + ovf_off);
        long long* sbuf    = (long long*)(ws + sbuf_off);

        // cursor..ovf_cnt are contiguous ints; zero them inside the GEMM kernel
        int zn = (int)((ovfc_off - cur_off) / sizeof(int)) + 1;
        gemm_xwt_zero<<<GEMM_BLOCKS, 256, 0, stream>>>(X, W, H, cursor, zn);
        scatter_padded<<<SCAT_BLOCKS, 256, 0, stream>>>(A_rows, A_cols, A_vals,
                                                        cursor, sbuf, slots, ovf_cnt, ovf);
        spmm_pull<<<(N_NODES + 3) / 4, 256, 0, stream>>>(nullptr, cursor,
                                                         (const int2*)sbuf, H, out, slots);
        fixup_ovf<<<16, 256, 0, stream>>>(ovf_cnt, ovf, A_rows, A_cols, A_vals, H, out);
    } else {
        // ---- exact-CSR fallback layout ----
        size_t o2 = h_bytes;
        size_t cnt_off = o2; o2 += align256(size_t(N_NODES) * sizeof(int));
        size_t cu2_off = o2; o2 += align256(size_t(N_NODES) * sizeof(int));
        size_t rs_off  = o2; o2 += align256(size_t(N_NODES + 1) * sizeof(int));
        size_t sb2_off = o2; o2 += size_t(N_EDGES) * sizeof(long long);

        int*       counts    = (int*)(ws + cnt_off);
        int*       cursor    = (int*)(ws + cu2_off);
        int*       row_start = (int*)(ws + rs_off);
        long long* sbuf      = (long long*)(ws + sb2_off);

        int zn = (int)((rs_off - cnt_off) / sizeof(int));  // counts+cursor
        gemm_xwt_zero<<<GEMM_BLOCKS, 256, 0, stream>>>(X, W, H, counts, zn);
        hist_rows<<<(N_EDGES + 255) / 256, 256, 0, stream>>>(A_rows, counts);
        scan_counts<<<1, 1024, 0, stream>>>(counts, row_start);
        scatter_exact<<<(N_EDGES + 255) / 256, 256, 0, stream>>>(A_rows, A_cols, A_vals,
                                                                 row_start, cursor, sbuf);
        spmm_pull<<<(N_NODES + 3) / 4, 256, 0, stream>>>(row_start, nullptr,
                                                         (const int2*)sbuf, H, out, 0);
    }
}